// Round 1
// baseline (3962.927 us; speedup 1.0000x reference)
//
#include <hip/hip_runtime.h>
#include <math.h>

#define NN 100000
#define NE 1600000
#define ETOT 1700000   // NE + NN self loops
#define DIN 264
#define DH 64
#define SLOPE 0.2f

// monotone float <-> uint mapping for atomicMax on floats
__device__ __forceinline__ unsigned f2u(float f) {
  unsigned b = __float_as_uint(f);
  return (b & 0x80000000u) ? ~b : (b | 0x80000000u);
}
__device__ __forceinline__ float u2f(unsigned u) {
  return __uint_as_float((u & 0x80000000u) ? (u ^ 0x80000000u) : ~u);
}

__global__ void k_mean(const float* __restrict__ ea, float* __restrict__ sum) {
  float acc = 0.f;
  for (int i = blockIdx.x * blockDim.x + threadIdx.x; i < NE; i += gridDim.x * blockDim.x)
    acc += ea[i];
  #pragma unroll
  for (int off = 32; off > 0; off >>= 1) acc += __shfl_xor(acc, off);
  __shared__ float s[4];
  int lane = threadIdx.x & 63, w = threadIdx.x >> 6;
  if (lane == 0) s[w] = acc;
  __syncthreads();
  if (threadIdx.x == 0) atomicAdd(sum, s[0] + s[1] + s[2] + s[3]);
}

// One wave computes 8 nodes x 64 dims for TWO weight matrices (Wl, Wr).
// lane j holds output dim j; x row chunks loaded as float4 (wave-uniform).
template <int K>
__global__ void k_gemm2(const float* __restrict__ X,
                        const float* __restrict__ Wl, const float* __restrict__ bl,
                        const float* __restrict__ Wr, const float* __restrict__ br,
                        float* __restrict__ xl, float* __restrict__ xr) {
  int wave = (blockIdx.x * blockDim.x + threadIdx.x) >> 6;
  int lane = threadIdx.x & 63;
  int n0 = wave * 8;             // NN % 8 == 0
  if (n0 >= NN) return;
  float accl[8] = {0, 0, 0, 0, 0, 0, 0, 0};
  float accr[8] = {0, 0, 0, 0, 0, 0, 0, 0};
  for (int k4 = 0; k4 < K; k4 += 4) {
    float4 xv[8];
    #pragma unroll
    for (int m = 0; m < 8; m++)
      xv[m] = *(const float4*)&X[(n0 + m) * K + k4];
    #pragma unroll
    for (int kk = 0; kk < 4; kk++) {
      float wl = Wl[(k4 + kk) * DH + lane];
      float wr = Wr[(k4 + kk) * DH + lane];
      #pragma unroll
      for (int m = 0; m < 8; m++) {
        float xvv = (&xv[m].x)[kk];
        accl[m] = fmaf(xvv, wl, accl[m]);
        accr[m] = fmaf(xvv, wr, accr[m]);
      }
    }
  }
  #pragma unroll
  for (int m = 0; m < 8; m++) {
    xl[(n0 + m) * DH + lane] = accl[m] + bl[lane];
    xr[(n0 + m) * DH + lane] = accr[m] + br[lane];
  }
}

// 16 lanes per edge; lane handles 4 dims via float4.
__global__ void k_logits(const int* __restrict__ ei, const float* __restrict__ ea,
                         const float* __restrict__ sump,
                         const float* __restrict__ xl, const float* __restrict__ xr,
                         const float* __restrict__ We, const float* __restrict__ att,
                         float* __restrict__ logits, unsigned* __restrict__ mx) {
  int g = (blockIdx.x * blockDim.x + threadIdx.x) >> 4;
  int l = threadIdx.x & 15;
  if (g >= ETOT) return;
  int s, d;
  float a;
  if (g < NE) {
    s = ei[g];
    d = ei[NE + g];
    a = ea[g];
  } else {
    s = d = g - NE;
    a = sump[0] * (1.0f / NE);
  }
  float4 vl = *(const float4*)&xl[s * DH + l * 4];
  float4 vr = *(const float4*)&xr[d * DH + l * 4];
  float4 we = *(const float4*)&We[l * 4];
  float4 at = *(const float4*)&att[l * 4];
  float p = 0.f, v;
  v = vr.x + vl.x + a * we.x; v = v > 0.f ? v : SLOPE * v; p += v * at.x;
  v = vr.y + vl.y + a * we.y; v = v > 0.f ? v : SLOPE * v; p += v * at.y;
  v = vr.z + vl.z + a * we.z; v = v > 0.f ? v : SLOPE * v; p += v * at.z;
  v = vr.w + vl.w + a * we.w; v = v > 0.f ? v : SLOPE * v; p += v * at.w;
  #pragma unroll
  for (int off = 8; off > 0; off >>= 1) p += __shfl_xor(p, off);
  if (l == 0) {
    logits[g] = p;
    atomicMax(&mx[d], f2u(p));
  }
}

__global__ void k_exp(const int* __restrict__ ei, const float* __restrict__ logits,
                      const unsigned* __restrict__ mx, float* __restrict__ ex,
                      float* __restrict__ den) {
  int g = blockIdx.x * blockDim.x + threadIdx.x;
  if (g >= ETOT) return;
  int d = (g < NE) ? ei[NE + g] : g - NE;
  float e = expf(logits[g] - u2f(mx[d]));
  ex[g] = e;
  atomicAdd(&den[d], e);
}

// 16 lanes per edge; per-dim ordered-uint atomicMax into out (segment max).
__global__ void k_aggr(const int* __restrict__ ei, const float* __restrict__ ex,
                       const float* __restrict__ den, const float* __restrict__ xl,
                       unsigned* __restrict__ outu) {
  int g = (blockIdx.x * blockDim.x + threadIdx.x) >> 4;
  int l = threadIdx.x & 15;
  if (g >= ETOT) return;
  int s, d;
  if (g < NE) {
    s = ei[g];
    d = ei[NE + g];
  } else {
    s = d = g - NE;
  }
  float alpha = ex[g] / den[d];
  float4 vl = *(const float4*)&xl[s * DH + l * 4];
  unsigned* o = outu + d * DH + l * 4;
  atomicMax(o + 0, f2u(vl.x * alpha));
  atomicMax(o + 1, f2u(vl.y * alpha));
  atomicMax(o + 2, f2u(vl.z * alpha));
  atomicMax(o + 3, f2u(vl.w * alpha));
}

// convert ordered-uint aggregate -> float, + bias, relu (in place)
__global__ void k_finish(unsigned* __restrict__ hu, const float* __restrict__ bias) {
  int i = blockIdx.x * blockDim.x + threadIdx.x;
  if (i >= NN * DH) return;
  float v = u2f(hu[i]) + bias[i & (DH - 1)];
  ((float*)hu)[i] = v > 0.f ? v : 0.f;
}

// out = relu(h@W3+b3) @ W4 + b4 ; one wave = 8 nodes
__global__ void k_head(const float* __restrict__ h, const float* __restrict__ W3,
                       const float* __restrict__ b3, const float* __restrict__ W4,
                       const float* __restrict__ b4, float* __restrict__ out) {
  int wave = (blockIdx.x * blockDim.x + threadIdx.x) >> 6;
  int lane = threadIdx.x & 63;
  int n0 = wave * 8;
  if (n0 >= NN) return;
  float acc[8] = {0, 0, 0, 0, 0, 0, 0, 0};
  for (int k4 = 0; k4 < DH; k4 += 4) {
    float4 hv[8];
    #pragma unroll
    for (int m = 0; m < 8; m++)
      hv[m] = *(const float4*)&h[(n0 + m) * DH + k4];
    #pragma unroll
    for (int kk = 0; kk < 4; kk++) {
      float w = W3[(k4 + kk) * DH + lane];
      #pragma unroll
      for (int m = 0; m < 8; m++)
        acc[m] = fmaf((&hv[m].x)[kk], w, acc[m]);
    }
  }
  float w4 = W4[lane];
  float b3v = b3[lane];
  float b4v = b4[0];
  #pragma unroll
  for (int m = 0; m < 8; m++) {
    float t = acc[m] + b3v;
    t = t > 0.f ? t : 0.f;
    float p = t * w4;
    #pragma unroll
    for (int off = 32; off > 0; off >>= 1) p += __shfl_xor(p, off);
    if (lane == 0) out[n0 + m] = p + b4v;
  }
}

extern "C" void kernel_launch(void* const* d_in, const int* in_sizes, int n_in,
                              void* d_out, int out_size, void* d_ws, size_t ws_size,
                              hipStream_t stream) {
  const float* x      = (const float*)d_in[0];
  const int*   ei     = (const int*)d_in[1];
  const float* ea     = (const float*)d_in[2];
  const float* l1_Wl  = (const float*)d_in[3];
  const float* l1_bl  = (const float*)d_in[4];
  const float* l1_Wr  = (const float*)d_in[5];
  const float* l1_br  = (const float*)d_in[6];
  const float* l1_We  = (const float*)d_in[7];
  const float* l1_att = (const float*)d_in[8];
  const float* l1_bias= (const float*)d_in[9];
  const float* l2_Wl  = (const float*)d_in[10];
  const float* l2_bl  = (const float*)d_in[11];
  const float* l2_Wr  = (const float*)d_in[12];
  const float* l2_br  = (const float*)d_in[13];
  const float* l2_We  = (const float*)d_in[14];
  const float* l2_att = (const float*)d_in[15];
  const float* l2_bias= (const float*)d_in[16];
  const float* W3     = (const float*)d_in[17];
  const float* b3     = (const float*)d_in[18];
  const float* W4     = (const float*)d_in[19];
  const float* b4     = (const float*)d_in[20];
  float* out = (float*)d_out;

  float*    ws     = (float*)d_ws;
  float*    sum    = ws;                       // 1 (padded to 256)
  float*    xl     = ws + 256;                 // NN*DH
  float*    xr     = xl + NN * DH;             // NN*DH
  float*    h      = xr + NN * DH;             // NN*DH (aggr buffer aliases h)
  float*    logits = h + NN * DH;              // ETOT
  float*    ex     = logits + ETOT;            // ETOT
  unsigned* mx     = (unsigned*)(ex + ETOT);   // NN
  float*    den    = (float*)(mx + NN);        // NN

  const int B = 256;
  const int gemm_blocks = (NN / 8 * 64) / B;            // 3125
  const int edge16_blocks = (ETOT * 16 + B - 1) / B;    // 106250
  const int edge1_blocks  = (ETOT + B - 1) / B;         // 6641
  const int node_blocks   = (NN * DH + B - 1) / B;      // 25000

  hipMemsetAsync(sum, 0, 256 * sizeof(float), stream);
  k_mean<<<256, B, 0, stream>>>(ea, sum);

  // ---- layer 1 ----
  k_gemm2<DIN><<<gemm_blocks, B, 0, stream>>>(x, l1_Wl, l1_bl, l1_Wr, l1_br, xl, xr);
  hipMemsetAsync(mx, 0, NN * sizeof(unsigned), stream);
  hipMemsetAsync(den, 0, NN * sizeof(float), stream);
  hipMemsetAsync(h, 0, NN * DH * sizeof(float), stream);
  k_logits<<<edge16_blocks, B, 0, stream>>>(ei, ea, sum, xl, xr, l1_We, l1_att, logits, mx);
  k_exp<<<edge1_blocks, B, 0, stream>>>(ei, logits, mx, ex, den);
  k_aggr<<<edge16_blocks, B, 0, stream>>>(ei, ex, den, xl, (unsigned*)h);
  k_finish<<<node_blocks, B, 0, stream>>>((unsigned*)h, l1_bias);

  // ---- layer 2 ----
  k_gemm2<DH><<<gemm_blocks, B, 0, stream>>>(h, l2_Wl, l2_bl, l2_Wr, l2_br, xl, xr);
  hipMemsetAsync(mx, 0, NN * sizeof(unsigned), stream);
  hipMemsetAsync(den, 0, NN * sizeof(float), stream);
  hipMemsetAsync(h, 0, NN * DH * sizeof(float), stream);
  k_logits<<<edge16_blocks, B, 0, stream>>>(ei, ea, sum, xl, xr, l2_We, l2_att, logits, mx);
  k_exp<<<edge1_blocks, B, 0, stream>>>(ei, logits, mx, ex, den);
  k_aggr<<<edge16_blocks, B, 0, stream>>>(ei, ex, den, xl, (unsigned*)h);
  k_finish<<<node_blocks, B, 0, stream>>>((unsigned*)h, l2_bias);

  // ---- head ----
  k_head<<<gemm_blocks, B, 0, stream>>>(h, W3, b3, W4, b4, out);
}

// Round 2
// 1844.529 us; speedup vs baseline: 2.1485x; 2.1485x over previous
//
#include <hip/hip_runtime.h>
#include <math.h>
#include <float.h>

#define NN 100000
#define NE 1600000
#define ETOT 1700000   // NE + NN self loops
#define DIN 264
#define DH 64
#define SLOPE 0.2f

__global__ void k_mean(const float* __restrict__ ea, float* __restrict__ sum) {
  float acc = 0.f;
  for (int i = blockIdx.x * blockDim.x + threadIdx.x; i < NE; i += gridDim.x * blockDim.x)
    acc += ea[i];
  #pragma unroll
  for (int off = 32; off > 0; off >>= 1) acc += __shfl_xor(acc, off);
  __shared__ float s[4];
  int lane = threadIdx.x & 63, w = threadIdx.x >> 6;
  if (lane == 0) s[w] = acc;
  __syncthreads();
  if (threadIdx.x == 0) atomicAdd(sum, s[0] + s[1] + s[2] + s[3]);
}

__global__ void k_hist(const int* __restrict__ ei, unsigned* __restrict__ deg) {
  int e = blockIdx.x * blockDim.x + threadIdx.x;
  if (e >= ETOT) return;
  int d = (e < NE) ? ei[NE + e] : e - NE;
  atomicAdd(&deg[d], 1u);
}

// single-block exclusive scan of deg -> rowptr (and wptr cursor copy)
__global__ void k_scan(const unsigned* __restrict__ deg, unsigned* __restrict__ rowptr,
                       unsigned* __restrict__ wptr) {
  __shared__ unsigned ls[1024];
  const int CH = (NN + 1023) / 1024;  // 98
  int t = threadIdx.x;
  int beg = t * CH, end = min(beg + CH, NN);
  unsigned s = 0;
  for (int i = beg; i < end; i++) s += deg[i];
  ls[t] = s;
  __syncthreads();
  for (int off = 1; off < 1024; off <<= 1) {
    unsigned v = (t >= off) ? ls[t - off] : 0u;
    __syncthreads();
    ls[t] += v;
    __syncthreads();
  }
  unsigned base = (t == 0) ? 0u : ls[t - 1];
  for (int i = beg; i < end; i++) {
    rowptr[i] = base;
    wptr[i] = base;
    base += deg[i];
  }
  if (t == 1023) rowptr[NN] = ls[1023];
}

__global__ void k_scatter(const int* __restrict__ ei, const float* __restrict__ ea,
                          const float* __restrict__ sump, unsigned* __restrict__ wptr,
                          int2* __restrict__ csr) {
  int e = blockIdx.x * blockDim.x + threadIdx.x;
  if (e >= ETOT) return;
  int s, d;
  float a;
  if (e < NE) {
    s = ei[e];
    d = ei[NE + e];
    a = ea[e];
  } else {
    s = d = e - NE;
    a = sump[0] * (1.0f / NE);
  }
  unsigned pos = atomicAdd(&wptr[d], 1u);
  csr[pos] = make_int2(s, __float_as_int(a));
}

// One wave computes 8 nodes x 64 dims for TWO weight matrices (Wl, Wr).
template <int K>
__global__ void k_gemm2(const float* __restrict__ X,
                        const float* __restrict__ Wl, const float* __restrict__ bl,
                        const float* __restrict__ Wr, const float* __restrict__ br,
                        float* __restrict__ xl, float* __restrict__ xr) {
  int wave = (blockIdx.x * blockDim.x + threadIdx.x) >> 6;
  int lane = threadIdx.x & 63;
  int n0 = wave * 8;  // NN % 8 == 0
  if (n0 >= NN) return;
  float accl[8] = {0, 0, 0, 0, 0, 0, 0, 0};
  float accr[8] = {0, 0, 0, 0, 0, 0, 0, 0};
  for (int k4 = 0; k4 < K; k4 += 4) {
    float4 xv[8];
    #pragma unroll
    for (int m = 0; m < 8; m++)
      xv[m] = *(const float4*)&X[(n0 + m) * K + k4];
    #pragma unroll
    for (int kk = 0; kk < 4; kk++) {
      float wl = Wl[(k4 + kk) * DH + lane];
      float wr = Wr[(k4 + kk) * DH + lane];
      #pragma unroll
      for (int m = 0; m < 8; m++) {
        float xvv = (&xv[m].x)[kk];
        accl[m] = fmaf(xvv, wl, accl[m]);
        accr[m] = fmaf(xvv, wr, accr[m]);
      }
    }
  }
  #pragma unroll
  for (int m = 0; m < 8; m++) {
    xl[(n0 + m) * DH + lane] = accl[m] + bl[lane];
    xr[(n0 + m) * DH + lane] = accr[m] + br[lane];
  }
}

// Fused per-node attention: 16 lanes own one dst node; online softmax + max-aggregate.
// h[n] = relu( max_e(xl[src_e]*exp(p_e-M)) / sum_e exp(p_e-M) + bias )
__global__ void k_attn(const unsigned* __restrict__ rowptr, const int2* __restrict__ csr,
                       const float* __restrict__ xl, const float* __restrict__ xr,
                       const float* __restrict__ We, const float* __restrict__ att,
                       const float* __restrict__ bias, float* __restrict__ h) {
  int n = (blockIdx.x * blockDim.x + threadIdx.x) >> 4;
  int l = threadIdx.x & 15;
  if (n >= NN) return;
  float4 xr4 = *(const float4*)&xr[n * DH + l * 4];
  float4 we4 = *(const float4*)&We[l * 4];
  float4 at4 = *(const float4*)&att[l * 4];
  int beg = rowptr[n], end = rowptr[n + 1];
  float M = 0.f, D = 0.f;
  float4 V = {0.f, 0.f, 0.f, 0.f};
  bool first = true;
  for (int e = beg; e < end; e++) {
    int2 c = csr[e];
    float a = __int_as_float(c.y);
    float4 sl = *(const float4*)&xl[c.x * DH + l * 4];
    float v, p = 0.f;
    v = xr4.x + sl.x + a * we4.x; v = v > 0.f ? v : SLOPE * v; p += v * at4.x;
    v = xr4.y + sl.y + a * we4.y; v = v > 0.f ? v : SLOPE * v; p += v * at4.y;
    v = xr4.z + sl.z + a * we4.z; v = v > 0.f ? v : SLOPE * v; p += v * at4.z;
    v = xr4.w + sl.w + a * we4.w; v = v > 0.f ? v : SLOPE * v; p += v * at4.w;
    p += __shfl_xor(p, 1);
    p += __shfl_xor(p, 2);
    p += __shfl_xor(p, 4);
    p += __shfl_xor(p, 8);
    if (first) {
      M = p;
      D = 1.f;
      V = sl;
      first = false;
    } else {
      float Mn = fmaxf(M, p);
      float sO = __expf(M - Mn), sN = __expf(p - Mn);
      D = D * sO + sN;
      V.x = fmaxf(V.x * sO, sl.x * sN);
      V.y = fmaxf(V.y * sO, sl.y * sN);
      V.z = fmaxf(V.z * sO, sl.z * sN);
      V.w = fmaxf(V.w * sO, sl.w * sN);
      M = Mn;
    }
  }
  float inv = 1.0f / D;
  float4 b4 = *(const float4*)&bias[l * 4];
  float4 o;
  o.x = fmaxf(V.x * inv + b4.x, 0.f);
  o.y = fmaxf(V.y * inv + b4.y, 0.f);
  o.z = fmaxf(V.z * inv + b4.z, 0.f);
  o.w = fmaxf(V.w * inv + b4.w, 0.f);
  *(float4*)&h[n * DH + l * 4] = o;
}

// out = relu(h@W3+b3) @ W4 + b4 ; one wave = 8 nodes
__global__ void k_head(const float* __restrict__ h, const float* __restrict__ W3,
                       const float* __restrict__ b3, const float* __restrict__ W4,
                       const float* __restrict__ b4, float* __restrict__ out) {
  int wave = (blockIdx.x * blockDim.x + threadIdx.x) >> 6;
  int lane = threadIdx.x & 63;
  int n0 = wave * 8;
  if (n0 >= NN) return;
  float acc[8] = {0, 0, 0, 0, 0, 0, 0, 0};
  for (int k4 = 0; k4 < DH; k4 += 4) {
    float4 hv[8];
    #pragma unroll
    for (int m = 0; m < 8; m++)
      hv[m] = *(const float4*)&h[(n0 + m) * DH + k4];
    #pragma unroll
    for (int kk = 0; kk < 4; kk++) {
      float w = W3[(k4 + kk) * DH + lane];
      #pragma unroll
      for (int m = 0; m < 8; m++)
        acc[m] = fmaf((&hv[m].x)[kk], w, acc[m]);
    }
  }
  float w4 = W4[lane];
  float b3v = b3[lane];
  float b4v = b4[0];
  #pragma unroll
  for (int m = 0; m < 8; m++) {
    float t = acc[m] + b3v;
    t = t > 0.f ? t : 0.f;
    float p = t * w4;
    #pragma unroll
    for (int off = 32; off > 0; off >>= 1) p += __shfl_xor(p, off);
    if (lane == 0) out[n0 + m] = p + b4v;
  }
}

extern "C" void kernel_launch(void* const* d_in, const int* in_sizes, int n_in,
                              void* d_out, int out_size, void* d_ws, size_t ws_size,
                              hipStream_t stream) {
  const float* x      = (const float*)d_in[0];
  const int*   ei     = (const int*)d_in[1];
  const float* ea     = (const float*)d_in[2];
  const float* l1_Wl  = (const float*)d_in[3];
  const float* l1_bl  = (const float*)d_in[4];
  const float* l1_Wr  = (const float*)d_in[5];
  const float* l1_br  = (const float*)d_in[6];
  const float* l1_We  = (const float*)d_in[7];
  const float* l1_att = (const float*)d_in[8];
  const float* l1_bias= (const float*)d_in[9];
  const float* l2_Wl  = (const float*)d_in[10];
  const float* l2_bl  = (const float*)d_in[11];
  const float* l2_Wr  = (const float*)d_in[12];
  const float* l2_br  = (const float*)d_in[13];
  const float* l2_We  = (const float*)d_in[14];
  const float* l2_att = (const float*)d_in[15];
  const float* l2_bias= (const float*)d_in[16];
  const float* W3     = (const float*)d_in[17];
  const float* b3     = (const float*)d_in[18];
  const float* W4     = (const float*)d_in[19];
  const float* b4     = (const float*)d_in[20];
  float* out = (float*)d_out;

  float*    ws     = (float*)d_ws;
  float*    sum    = ws;                        // 256 floats (only [0] used)
  float*    xl     = ws + 256;                  // NN*DH
  float*    xr     = xl + NN * DH;              // NN*DH
  float*    h      = xr + NN * DH;              // NN*DH
  int2*     csr    = (int2*)(h + NN * DH);      // ETOT int2 (8B aligned)
  unsigned* rowptr = (unsigned*)(csr + ETOT);   // NN+1
  unsigned* wptr   = rowptr + NN + 1;           // NN
  unsigned* deg    = wptr + NN;                 // NN

  const int B = 256;
  const int gemm_blocks  = (NN / 8 * 64) / B;          // 3125
  const int edge_blocks  = (ETOT + B - 1) / B;         // 6641
  const int attn_blocks  = (NN * 16 + B - 1) / B;      // 6250

  // ---- graph preprocessing (once per call; shared by both layers) ----
  hipMemsetAsync(sum, 0, 256 * sizeof(float), stream);
  hipMemsetAsync(deg, 0, NN * sizeof(unsigned), stream);
  k_mean<<<256, B, 0, stream>>>(ea, sum);
  k_hist<<<edge_blocks, B, 0, stream>>>(ei, deg);
  k_scan<<<1, 1024, 0, stream>>>(deg, rowptr, wptr);
  k_scatter<<<edge_blocks, B, 0, stream>>>(ei, ea, sum, wptr, csr);

  // ---- layer 1 ----
  k_gemm2<DIN><<<gemm_blocks, B, 0, stream>>>(x, l1_Wl, l1_bl, l1_Wr, l1_br, xl, xr);
  k_attn<<<attn_blocks, B, 0, stream>>>(rowptr, csr, xl, xr, l1_We, l1_att, l1_bias, h);

  // ---- layer 2 ----
  k_gemm2<DH><<<gemm_blocks, B, 0, stream>>>(h, l2_Wl, l2_bl, l2_Wr, l2_br, xl, xr);
  k_attn<<<attn_blocks, B, 0, stream>>>(rowptr, csr, xl, xr, l2_We, l2_att, l2_bias, h);

  // ---- head ----
  k_head<<<gemm_blocks, B, 0, stream>>>(h, W3, b3, W4, b4, out);
}

// Round 3
// 1505.820 us; speedup vs baseline: 2.6317x; 1.2249x over previous
//
#include <hip/hip_runtime.h>
#include <math.h>
#include <float.h>

#define NN 100000
#define NE 1600000
#define ETOT 1700000   // NE + NN self loops
#define DIN 264
#define DH 64
#define SLOPE 0.2f

__global__ void k_mean(const float* __restrict__ ea, float* __restrict__ sum) {
  float acc = 0.f;
  for (int i = blockIdx.x * blockDim.x + threadIdx.x; i < NE; i += gridDim.x * blockDim.x)
    acc += ea[i];
  #pragma unroll
  for (int off = 32; off > 0; off >>= 1) acc += __shfl_xor(acc, off);
  __shared__ float s[4];
  int lane = threadIdx.x & 63, w = threadIdx.x >> 6;
  if (lane == 0) s[w] = acc;
  __syncthreads();
  if (threadIdx.x == 0) atomicAdd(sum, s[0] + s[1] + s[2] + s[3]);
}

__global__ void k_hist(const int* __restrict__ ei, unsigned* __restrict__ deg) {
  int e = blockIdx.x * blockDim.x + threadIdx.x;
  if (e >= ETOT) return;
  int d = (e < NE) ? ei[NE + e] : e - NE;
  atomicAdd(&deg[d], 1u);
}

// single-block exclusive scan of deg -> rowptr (and wptr cursor copy)
__global__ void k_scan(const unsigned* __restrict__ deg, unsigned* __restrict__ rowptr,
                       unsigned* __restrict__ wptr) {
  __shared__ unsigned ls[1024];
  const int CH = (NN + 1023) / 1024;  // 98
  int t = threadIdx.x;
  int beg = t * CH, end = min(beg + CH, NN);
  unsigned s = 0;
  for (int i = beg; i < end; i++) s += deg[i];
  ls[t] = s;
  __syncthreads();
  for (int off = 1; off < 1024; off <<= 1) {
    unsigned v = (t >= off) ? ls[t - off] : 0u;
    __syncthreads();
    ls[t] += v;
    __syncthreads();
  }
  unsigned base = (t == 0) ? 0u : ls[t - 1];
  for (int i = beg; i < end; i++) {
    rowptr[i] = base;
    wptr[i] = base;
    base += deg[i];
  }
  if (t == 1023) rowptr[NN] = ls[1023];
}

__global__ void k_scatter(const int* __restrict__ ei, const float* __restrict__ ea,
                          const float* __restrict__ sump, unsigned* __restrict__ wptr,
                          int2* __restrict__ csr) {
  int e = blockIdx.x * blockDim.x + threadIdx.x;
  if (e >= ETOT) return;
  int s, d;
  float a;
  if (e < NE) {
    s = ei[e];
    d = ei[NE + e];
    a = ea[e];
  } else {
    s = d = e - NE;
    a = sump[0] * (1.0f / NE);
  }
  unsigned pos = atomicAdd(&wptr[d], 1u);
  csr[pos] = make_int2(s, __float_as_int(a));
}

// One wave computes 8 nodes x 64 dims for TWO weight matrices (Wl, Wr).
// X loads: coalesced 128B per 8-lane group; values broadcast to lanes via shfl.
template <int K>
__global__ void k_gemm2(const float* __restrict__ X,
                        const float* __restrict__ Wl, const float* __restrict__ bl,
                        const float* __restrict__ Wr, const float* __restrict__ br,
                        float* __restrict__ xl, float* __restrict__ xr) {
  int wave = (blockIdx.x * blockDim.x + threadIdx.x) >> 6;
  int lane = threadIdx.x & 63;
  int n0 = wave * 8;  // NN % 8 == 0, exact
  if (n0 >= NN) return;
  int lrow = lane >> 3;        // which of the 8 nodes this lane helps load
  int lcol = (lane & 7) * 4;   // float4 offset within a 32-col chunk
  float accl[8] = {0, 0, 0, 0, 0, 0, 0, 0};
  float accr[8] = {0, 0, 0, 0, 0, 0, 0, 0};
  constexpr int KBF = (K / 32) * 32;
  for (int kb = 0; kb < KBF; kb += 32) {
    float4 xv = *(const float4*)&X[(n0 + lrow) * K + kb + lcol];
    #pragma unroll
    for (int kk = 0; kk < 32; kk++) {
      float wl = Wl[(kb + kk) * DH + lane];
      float wr = Wr[(kb + kk) * DH + lane];
      #pragma unroll
      for (int m = 0; m < 8; m++) {
        float bx = __shfl((&xv.x)[kk & 3], m * 8 + (kk >> 2));
        accl[m] = fmaf(bx, wl, accl[m]);
        accr[m] = fmaf(bx, wr, accr[m]);
      }
    }
  }
  // tail columns (K=264 -> 8 cols); tiny, uniform loads acceptable here
  for (int k4 = KBF; k4 < K; k4 += 4) {
    float4 xm[8];
    #pragma unroll
    for (int m = 0; m < 8; m++)
      xm[m] = *(const float4*)&X[(n0 + m) * K + k4];
    #pragma unroll
    for (int kk = 0; kk < 4; kk++) {
      float wl = Wl[(k4 + kk) * DH + lane];
      float wr = Wr[(k4 + kk) * DH + lane];
      #pragma unroll
      for (int m = 0; m < 8; m++) {
        float xc = (&xm[m].x)[kk];
        accl[m] = fmaf(xc, wl, accl[m]);
        accr[m] = fmaf(xc, wr, accr[m]);
      }
    }
  }
  #pragma unroll
  for (int m = 0; m < 8; m++) {
    xl[(n0 + m) * DH + lane] = accl[m] + bl[lane];
    xr[(n0 + m) * DH + lane] = accr[m] + br[lane];
  }
}

// Fused per-node attention: 16 lanes own one dst node; online softmax + max-aggregate.
// Edge loop: cooperative coalesced csr chunk loads + 4-edge gather batches.
// HEAD=true additionally computes out[n] = relu(h@W3+b3)@W4+b4 (no h write).
template <bool HEAD>
__global__ void k_attn(const unsigned* __restrict__ rowptr, const int2* __restrict__ csr,
                       const float* __restrict__ xl, const float* __restrict__ xr,
                       const float* __restrict__ We, const float* __restrict__ att,
                       const float* __restrict__ bias, float* __restrict__ h,
                       const float* __restrict__ W3, const float* __restrict__ b3,
                       const float* __restrict__ W4, const float* __restrict__ b4,
                       float* __restrict__ out) {
  int n = (blockIdx.x * blockDim.x + threadIdx.x) >> 4;
  int l = threadIdx.x & 15;
  int g0 = threadIdx.x & 48;  // 16-lane group base within the wave
  if (n >= NN) return;        // exact division: never taken, no partial groups
  int l4 = l * 4;
  float4 xr4 = *(const float4*)&xr[n * DH + l4];
  float4 we4 = *(const float4*)&We[l4];
  float4 at4 = *(const float4*)&att[l4];
  int beg = rowptr[n], end = rowptr[n + 1];  // deg >= 1 (self loop)
  float M, D;
  float4 V;
  {  // peel first edge
    int2 c0 = csr[beg];
    float a = __int_as_float(c0.y);
    float4 sl = *(const float4*)&xl[c0.x * DH + l4];
    float v, p = 0.f;
    v = xr4.x + sl.x + a * we4.x; v = v > 0.f ? v : SLOPE * v; p += v * at4.x;
    v = xr4.y + sl.y + a * we4.y; v = v > 0.f ? v : SLOPE * v; p += v * at4.y;
    v = xr4.z + sl.z + a * we4.z; v = v > 0.f ? v : SLOPE * v; p += v * at4.z;
    v = xr4.w + sl.w + a * we4.w; v = v > 0.f ? v : SLOPE * v; p += v * at4.w;
    p += __shfl_xor(p, 1);
    p += __shfl_xor(p, 2);
    p += __shfl_xor(p, 4);
    p += __shfl_xor(p, 8);
    M = p; D = 1.f; V = sl;
  }
  for (int e0 = beg + 1; e0 < end; e0 += 16) {
    int2 cl = csr[min(e0 + l, end - 1)];  // coalesced 128B per group
    int cnt = min(16, end - e0);
    for (int i = 0; i < cnt; i += 4) {
      int mm = min(4, cnt - i);
      float4 sl[4];
      float av[4];
      #pragma unroll
      for (int j = 0; j < 4; j++) {
        if (j < mm) {
          int s = __shfl(cl.x, g0 + i + j);
          av[j] = __int_as_float(__shfl(cl.y, g0 + i + j));
          sl[j] = *(const float4*)&xl[s * DH + l4];  // 4 gathers in flight
        }
      }
      #pragma unroll
      for (int j = 0; j < 4; j++) {
        if (j < mm) {
          float a = av[j];
          float v, p = 0.f;
          v = xr4.x + sl[j].x + a * we4.x; v = v > 0.f ? v : SLOPE * v; p += v * at4.x;
          v = xr4.y + sl[j].y + a * we4.y; v = v > 0.f ? v : SLOPE * v; p += v * at4.y;
          v = xr4.z + sl[j].z + a * we4.z; v = v > 0.f ? v : SLOPE * v; p += v * at4.z;
          v = xr4.w + sl[j].w + a * we4.w; v = v > 0.f ? v : SLOPE * v; p += v * at4.w;
          p += __shfl_xor(p, 1);
          p += __shfl_xor(p, 2);
          p += __shfl_xor(p, 4);
          p += __shfl_xor(p, 8);
          float Mn = fmaxf(M, p);
          float sO = __expf(M - Mn), sN = __expf(p - Mn);
          D = D * sO + sN;
          V.x = fmaxf(V.x * sO, sl[j].x * sN);
          V.y = fmaxf(V.y * sO, sl[j].y * sN);
          V.z = fmaxf(V.z * sO, sl[j].z * sN);
          V.w = fmaxf(V.w * sO, sl[j].w * sN);
          M = Mn;
        }
      }
    }
  }
  float inv = 1.0f / D;
  float4 b = *(const float4*)&bias[l4];
  float4 o;
  o.x = fmaxf(V.x * inv + b.x, 0.f);
  o.y = fmaxf(V.y * inv + b.y, 0.f);
  o.z = fmaxf(V.z * inv + b.z, 0.f);
  o.w = fmaxf(V.w * inv + b.w, 0.f);
  if (!HEAD) {
    *(float4*)&h[n * DH + l4] = o;
  } else {
    // out[n] = relu(o @ W3 + b3) @ W4 + b4 ; lane l owns dims j = l4..l4+3
    float4 acc = {0.f, 0.f, 0.f, 0.f};
    #pragma unroll
    for (int kk = 0; kk < 16; kk++) {
      float4 hk;
      hk.x = __shfl(o.x, g0 + kk);
      hk.y = __shfl(o.y, g0 + kk);
      hk.z = __shfl(o.z, g0 + kk);
      hk.w = __shfl(o.w, g0 + kk);
      #pragma unroll
      for (int c = 0; c < 4; c++) {
        float4 w = *(const float4*)&W3[(kk * 4 + c) * DH + l4];
        float hv = (&hk.x)[c];
        acc.x = fmaf(hv, w.x, acc.x);
        acc.y = fmaf(hv, w.y, acc.y);
        acc.z = fmaf(hv, w.z, acc.z);
        acc.w = fmaf(hv, w.w, acc.w);
      }
    }
    float4 b3v = *(const float4*)&b3[l4];
    float4 w4v = *(const float4*)&W4[l4];
    float t, p = 0.f;
    t = acc.x + b3v.x; t = t > 0.f ? t : 0.f; p += t * w4v.x;
    t = acc.y + b3v.y; t = t > 0.f ? t : 0.f; p += t * w4v.y;
    t = acc.z + b3v.z; t = t > 0.f ? t : 0.f; p += t * w4v.z;
    t = acc.w + b3v.w; t = t > 0.f ? t : 0.f; p += t * w4v.w;
    p += __shfl_xor(p, 1);
    p += __shfl_xor(p, 2);
    p += __shfl_xor(p, 4);
    p += __shfl_xor(p, 8);
    if (l == 0) out[n] = p + b4[0];
  }
}

extern "C" void kernel_launch(void* const* d_in, const int* in_sizes, int n_in,
                              void* d_out, int out_size, void* d_ws, size_t ws_size,
                              hipStream_t stream) {
  const float* x      = (const float*)d_in[0];
  const int*   ei     = (const int*)d_in[1];
  const float* ea     = (const float*)d_in[2];
  const float* l1_Wl  = (const float*)d_in[3];
  const float* l1_bl  = (const float*)d_in[4];
  const float* l1_Wr  = (const float*)d_in[5];
  const float* l1_br  = (const float*)d_in[6];
  const float* l1_We  = (const float*)d_in[7];
  const float* l1_att = (const float*)d_in[8];
  const float* l1_bias= (const float*)d_in[9];
  const float* l2_Wl  = (const float*)d_in[10];
  const float* l2_bl  = (const float*)d_in[11];
  const float* l2_Wr  = (const float*)d_in[12];
  const float* l2_br  = (const float*)d_in[13];
  const float* l2_We  = (const float*)d_in[14];
  const float* l2_att = (const float*)d_in[15];
  const float* l2_bias= (const float*)d_in[16];
  const float* W3     = (const float*)d_in[17];
  const float* b3     = (const float*)d_in[18];
  const float* W4     = (const float*)d_in[19];
  const float* b4     = (const float*)d_in[20];
  float* out = (float*)d_out;

  float*    ws     = (float*)d_ws;
  float*    sum    = ws;                        // 256 floats (only [0] used)
  float*    xl     = ws + 256;                  // NN*DH
  float*    xr     = xl + NN * DH;              // NN*DH
  float*    h      = xr + NN * DH;              // NN*DH
  int2*     csr    = (int2*)(h + NN * DH);      // ETOT int2 (8B aligned)
  unsigned* rowptr = (unsigned*)(csr + ETOT);   // NN+1
  unsigned* wptr   = rowptr + NN + 1;           // NN
  unsigned* deg    = wptr + NN;                 // NN

  const int B = 256;
  const int gemm_blocks = (NN / 8 * 64) / B;        // 3125
  const int edge_blocks = (ETOT + B - 1) / B;       // 6641
  const int attn_blocks = (NN * 16) / B;            // 6250

  // ---- graph preprocessing (once per call; shared by both layers) ----
  hipMemsetAsync(sum, 0, 256 * sizeof(float), stream);
  hipMemsetAsync(deg, 0, NN * sizeof(unsigned), stream);
  k_mean<<<256, B, 0, stream>>>(ea, sum);
  k_hist<<<edge_blocks, B, 0, stream>>>(ei, deg);
  k_scan<<<1, 1024, 0, stream>>>(deg, rowptr, wptr);
  k_scatter<<<edge_blocks, B, 0, stream>>>(ei, ea, sum, wptr, csr);

  // ---- layer 1 ----
  k_gemm2<DIN><<<gemm_blocks, B, 0, stream>>>(x, l1_Wl, l1_bl, l1_Wr, l1_br, xl, xr);
  k_attn<false><<<attn_blocks, B, 0, stream>>>(rowptr, csr, xl, xr, l1_We, l1_att,
                                               l1_bias, h, W3, b3, W4, b4, out);

  // ---- layer 2 + head (fused) ----
  k_gemm2<DH><<<gemm_blocks, B, 0, stream>>>(h, l2_Wl, l2_bl, l2_Wr, l2_br, xl, xr);
  k_attn<true><<<attn_blocks, B, 0, stream>>>(rowptr, csr, xl, xr, l2_We, l2_att,
                                              l2_bias, h, W3, b3, W4, b4, out);
}